// Round 3
// baseline (124.441 us; speedup 1.0000x reference)
//
#include <hip/hip_runtime.h>

// s = sum_{b,i,j} X[b,i] W[i,j] G[b,i/128,j/128]; out = s^2.
// Factor over j:  s = sum_{i,jb} Wsum[i,jb] * H[i,jb],
//   Wsum[i,jb] = sum_{c<128} W[i, jb*128+c]
//   H[i,jb]    = sum_b X[b,i] * G[b, i/128, jb]
// K1: Wsum (HBM-bound, 28.3 MB mandatory read).
// K2: lane<->i mapping; 8 b's per wave -> 4608 waves (18 waves/CU) so VMEM
//     latency is hidden by TLP, not register-busting unrolls. Finish folded in.

#define B_DIM 1536
#define DI    1536
#define DO    4608
#define NI    12
#define NJ    36
#define GROW  (NI * NJ)            // 432 floats per G batch-row
#define BPW   8                    // b's per wave in kernel 2
#define K2_WAVES  (24 * (B_DIM / BPW))   // 24 i-blocks x 192 b-ranges = 4608
#define K2_BLOCKS (K2_WAVES / 4)         // 1152

// ---- Kernel 1: Wsum[i][jb]; wave handles (i, jb-pair); lane loads float4 ----
__global__ __launch_bounds__(256) void wsum_kernel(const float* __restrict__ W,
                                                   float* __restrict__ Wsum,
                                                   float* __restrict__ acc,
                                                   unsigned* __restrict__ counter) {
    if (blockIdx.x == 0 && threadIdx.x == 0) { *acc = 0.f; *counter = 0u; }
    int g    = blockIdx.x * 4 + (threadIdx.x >> 6);  // global wave id, 27648 total
    int lane = threadIdx.x & 63;
    int i = g / 18;          // row
    int w = g - i * 18;      // jb-pair: covers jb = 2w, 2w+1 (256 floats, 1 KB)
    const float4* p = (const float4*)(W + (size_t)i * DO + (size_t)w * 256);
    float4 v = p[lane];
    float s = (v.x + v.y) + (v.z + v.w);
    #pragma unroll
    for (int off = 16; off > 0; off >>= 1) s += __shfl_xor(s, off, 64);
    if (lane == 0)  Wsum[i * NJ + 2 * w]     = s;
    if (lane == 32) Wsum[i * NJ + 2 * w + 1] = s;
}

// ---- Kernel 2: H-accumulate + dot with Wsum + grid reduction + square ----
__global__ __launch_bounds__(256) void gated_kernel(const float* __restrict__ X,
                                                    const float* __restrict__ G,
                                                    const float* __restrict__ Wsum,
                                                    float* __restrict__ acc,
                                                    unsigned* __restrict__ counter,
                                                    float* __restrict__ out) {
    __shared__ float red[4];
    const int t    = threadIdx.x;
    const int w    = t >> 6;
    const int lane = t & 63;
    const int wave = blockIdx.x * 4 + w;     // 0..4607
    const int iblk = wave % 24;              // 64-wide i-block
    const int brng = wave / 24;              // 0..191, BPW b's each
    const int b0   = brng * BPW;
    const int i    = iblk * 64 + lane;
    const int ib   = iblk >> 1;              // uniform within wave

    float acc36[NJ];
    #pragma unroll
    for (int k = 0; k < NJ; ++k) acc36[k] = 0.f;

    const float* xp  = X + (size_t)b0 * DI + i;
    const float4* gp = (const float4*)(G + (size_t)b0 * GROW + (size_t)ib * NJ);
    const int gstride4 = GROW / 4;           // 108 float4 per batch-row

    // unroll 2: ~2 iterations of loads in flight (~120 VGPR) -> 4 waves/SIMD;
    // the other latency hiding comes from 18 resident waves/CU (1152 blocks).
    #pragma unroll 2
    for (int bb = 0; bb < BPW; ++bb) {
        const float4* g4 = gp + (size_t)bb * gstride4;
        float4 gv[9];
        #pragma unroll
        for (int k4 = 0; k4 < 9; ++k4) gv[k4] = g4[k4];
        float x = xp[(size_t)bb * DI];       // coalesced, lane<->i
        #pragma unroll
        for (int k4 = 0; k4 < 9; ++k4) {
            acc36[4*k4+0] = fmaf(x, gv[k4].x, acc36[4*k4+0]);
            acc36[4*k4+1] = fmaf(x, gv[k4].y, acc36[4*k4+1]);
            acc36[4*k4+2] = fmaf(x, gv[k4].z, acc36[4*k4+2]);
            acc36[4*k4+3] = fmaf(x, gv[k4].w, acc36[4*k4+3]);
        }
    }

    // per-lane dot with Wsum row i (L2-resident, 144 B per lane)
    float s = 0.f;
    const float4* wsv = (const float4*)(Wsum + (size_t)i * NJ);
    #pragma unroll
    for (int k4 = 0; k4 < 9; ++k4) {
        float4 w4 = wsv[k4];
        s += w4.x * acc36[4*k4] + w4.y * acc36[4*k4+1]
           + w4.z * acc36[4*k4+2] + w4.w * acc36[4*k4+3];
    }
    #pragma unroll
    for (int off = 1; off < 64; off <<= 1) s += __shfl_xor(s, off, 64);
    if (lane == 0) red[w] = s;
    __syncthreads();
    if (t == 0) {
        float bs = (red[0] + red[1]) + (red[2] + red[3]);
        atomicAdd(acc, bs);
        __threadfence();
        unsigned old = atomicAdd(counter, 1u);
        if (old == (unsigned)gridDim.x - 1u) {
            float tot = atomicAdd(acc, 0.0f);  // device-coherent read
            out[0] = tot * tot;
        }
    }
}

extern "C" void kernel_launch(void* const* d_in, const int* in_sizes, int n_in,
                              void* d_out, int out_size, void* d_ws, size_t ws_size,
                              hipStream_t stream) {
    const float* X = (const float*)d_in[0];  // [1536,1536]
    const float* W = (const float*)d_in[1];  // [1536,4608]
    const float* G = (const float*)d_in[2];  // [1536,12,36]
    float* out = (float*)d_out;

    float*    Wsum    = (float*)d_ws;                       // 55296 floats
    float*    acc     = Wsum + (size_t)DI * NJ;             // 1 float
    unsigned* counter = (unsigned*)(acc + 1);               // 1 uint

    // Kernel 1: 27648 waves = 6912 blocks x 4 waves (also zeroes acc/counter).
    wsum_kernel<<<(DI * 18) / 4, 256, 0, stream>>>(W, Wsum, acc, counter);
    // Kernel 2: 1152 blocks x 256 threads; writes out = s^2 from the last block.
    gated_kernel<<<K2_BLOCKS, 256, 0, stream>>>(X, G, Wsum, acc, counter, out);
}

// Round 4
// 114.739 us; speedup vs baseline: 1.0846x; 1.0846x over previous
//
#include <hip/hip_runtime.h>

// s = sum_{b,i,j} X[b,i] W[i,j] G[b,i/128,j/128]; out = s^2.
// Factor over j:  s = sum_{i,jb} Wsum[i,jb] * H[i,jb],
//   Wsum[i,jb] = sum_{c<128} W[i, jb*128+c]
//   H[i,jb]    = sum_b X[b,i] * G[b, i/128, jb]
// K1: Wsum (HBM-bound, 28.3 MB mandatory read).
// K2: lane<->i; per-b we compute s += x * dot36(WsumRow_i, G_row) with the
//     Wsum row held loop-invariant in VGPRs. Live state ~55 VGPRs -> no spill
//     (round-3 post-mortem: 36 H-accumulators + staged G hit a 40-VGPR budget
//     and spilled to scratch, 50 us). Finish (square) folded in via counter.

#define B_DIM 1536
#define DI    1536
#define DO    4608
#define NI    12
#define NJ    36
#define GROW  (NI * NJ)            // 432 floats per G batch-row
#define BPW   8                    // b's per wave in kernel 2
#define K2_WAVES  (24 * (B_DIM / BPW))   // 24 i-blocks x 192 b-ranges = 4608
#define K2_BLOCKS (K2_WAVES / 4)         // 1152

// ---- Kernel 1: Wsum[i][jb]; wave handles (i, jb-pair); lane loads float4 ----
__global__ __launch_bounds__(256) void wsum_kernel(const float* __restrict__ W,
                                                   float* __restrict__ Wsum,
                                                   float* __restrict__ acc,
                                                   unsigned* __restrict__ counter) {
    if (blockIdx.x == 0 && threadIdx.x == 0) { *acc = 0.f; *counter = 0u; }
    int g    = blockIdx.x * 4 + (threadIdx.x >> 6);  // global wave id, 27648 total
    int lane = threadIdx.x & 63;
    int i = g / 18;          // row
    int w = g - i * 18;      // jb-pair: covers jb = 2w, 2w+1 (256 floats, 1 KB)
    const float4* p = (const float4*)(W + (size_t)i * DO + (size_t)w * 256);
    float4 v = p[lane];
    float s = (v.x + v.y) + (v.z + v.w);
    #pragma unroll
    for (int off = 16; off > 0; off >>= 1) s += __shfl_xor(s, off, 64);
    if (lane == 0)  Wsum[i * NJ + 2 * w]     = s;
    if (lane == 32) Wsum[i * NJ + 2 * w + 1] = s;
}

// ---- Kernel 2: s += x * dot36(WsumRow, Grow); grid reduction + square ----
__global__ __launch_bounds__(256) void gated_kernel(const float* __restrict__ X,
                                                    const float* __restrict__ G,
                                                    const float* __restrict__ Wsum,
                                                    float* __restrict__ acc,
                                                    unsigned* __restrict__ counter,
                                                    float* __restrict__ out) {
    __shared__ float red[4];
    const int t    = threadIdx.x;
    const int w    = __builtin_amdgcn_readfirstlane(t >> 6);  // uniform wave id
    const int lane = t & 63;
    const int wave = blockIdx.x * 4 + w;     // 0..4607
    const int iblk = wave % 24;              // 64-wide i-block
    const int brng = wave / 24;              // 0..191, BPW b's each
    const int b0   = brng * BPW;
    const int i    = iblk * 64 + lane;
    const int ib   = iblk >> 1;              // uniform within wave

    // Loop-invariant Wsum row for this lane's i (144 B, L2/L3-hit).
    float4 wv[9];
    const float4* wsv = (const float4*)(Wsum + (size_t)i * NJ);
    #pragma unroll
    for (int k4 = 0; k4 < 9; ++k4) wv[k4] = wsv[k4];

    const float* xp    = X + (size_t)b0 * DI + i;     // coalesced, lane<->i
    const float* gbase = G + (size_t)b0 * GROW + (size_t)ib * NJ;  // wave-uniform

    float s = 0.f;
    #pragma unroll
    for (int bb = 0; bb < BPW; ++bb) {
        const float4* g4 = (const float4*)(gbase + (size_t)bb * GROW);
        float x = xp[(size_t)bb * DI];
        float d0 = 0.f, d1 = 0.f;     // two partials halve the dep chain
        #pragma unroll
        for (int k4 = 0; k4 < 9; ++k4) {
            float4 gv = g4[k4];       // uniform address -> scalar-load eligible
            d0 = fmaf(wv[k4].x, gv.x, d0);
            d1 = fmaf(wv[k4].y, gv.y, d1);
            d0 = fmaf(wv[k4].z, gv.z, d0);
            d1 = fmaf(wv[k4].w, gv.w, d1);
        }
        s = fmaf(x, d0 + d1, s);
    }

    #pragma unroll
    for (int off = 1; off < 64; off <<= 1) s += __shfl_xor(s, off, 64);
    if (lane == 0) red[w] = s;
    __syncthreads();
    if (t == 0) {
        float bs = (red[0] + red[1]) + (red[2] + red[3]);
        atomicAdd(acc, bs);
        __threadfence();
        unsigned old = atomicAdd(counter, 1u);
        if (old == (unsigned)gridDim.x - 1u) {
            float tot = atomicAdd(acc, 0.0f);  // device-coherent read
            out[0] = tot * tot;
        }
    }
}

extern "C" void kernel_launch(void* const* d_in, const int* in_sizes, int n_in,
                              void* d_out, int out_size, void* d_ws, size_t ws_size,
                              hipStream_t stream) {
    const float* X = (const float*)d_in[0];  // [1536,1536]
    const float* W = (const float*)d_in[1];  // [1536,4608]
    const float* G = (const float*)d_in[2];  // [1536,12,36]
    float* out = (float*)d_out;

    float*    Wsum    = (float*)d_ws;                       // 55296 floats
    float*    acc     = Wsum + (size_t)DI * NJ;             // 1 float
    unsigned* counter = (unsigned*)(acc + 1);               // 1 uint

    // Kernel 1: 27648 waves = 6912 blocks x 4 waves (also zeroes acc/counter).
    wsum_kernel<<<(DI * 18) / 4, 256, 0, stream>>>(W, Wsum, acc, counter);
    // Kernel 2: 1152 blocks x 256 threads; writes out = s^2 from the last block.
    gated_kernel<<<K2_BLOCKS, 256, 0, stream>>>(X, G, Wsum, acc, counter, out);
}

// Round 5
// 90.883 us; speedup vs baseline: 1.3692x; 1.2625x over previous
//
#include <hip/hip_runtime.h>

// s = sum_{b,i,j} X[b,i] W[i,j] G[b,i/128,j/128]; out = s^2.
// Factor over j:  s = sum_{i,jb} Wsum[i,jb] * H[i,jb],
//   Wsum[i,jb] = sum_{c<128} W[i, jb*128+c]
//   H[i,jb]    = sum_b X[b,i] * G[b, i/128, jb]
// K1: Wsum (HBM-bound, 28.3 MB mandatory read).
// K2: lane<->i; per-b: s += x * dot36(WsumRow_i, G_row), Wsum row loop-
//     invariant in VGPRs (R4: VGPR=32, no spills). NO grid atomics: R4
//     post-mortem showed 1152 blocks x (2 atomicAdd + threadfence) on two hot
//     cachelines ping-ponging across 8 XCD L2s cost ~44 us (~19 ns/RMW).
//     Each block writes one plain float partial instead.
// K3: 1-block finish: reduce 1152 partials, square.

#define B_DIM 1536
#define DI    1536
#define DO    4608
#define NI    12
#define NJ    36
#define GROW  (NI * NJ)            // 432 floats per G batch-row
#define BPW   8                    // b's per wave in kernel 2
#define K2_WAVES  (24 * (B_DIM / BPW))   // 24 i-blocks x 192 b-ranges = 4608
#define K2_BLOCKS (K2_WAVES / 4)         // 1152

// ---- Kernel 1: Wsum[i][jb]; wave handles (i, jb-pair); lane loads float4 ----
__global__ __launch_bounds__(256) void wsum_kernel(const float* __restrict__ W,
                                                   float* __restrict__ Wsum) {
    int g    = blockIdx.x * 4 + (threadIdx.x >> 6);  // global wave id, 27648 total
    int lane = threadIdx.x & 63;
    int i = g / 18;          // row
    int w = g - i * 18;      // jb-pair: covers jb = 2w, 2w+1 (256 floats, 1 KB)
    const float4* p = (const float4*)(W + (size_t)i * DO + (size_t)w * 256);
    float4 v = p[lane];
    float s = (v.x + v.y) + (v.z + v.w);
    #pragma unroll
    for (int off = 16; off > 0; off >>= 1) s += __shfl_xor(s, off, 64);
    if (lane == 0)  Wsum[i * NJ + 2 * w]     = s;
    if (lane == 32) Wsum[i * NJ + 2 * w + 1] = s;
}

// ---- Kernel 2: s += x * dot36(WsumRow, Grow); plain per-block partial ----
__global__ __launch_bounds__(256) void gated_kernel(const float* __restrict__ X,
                                                    const float* __restrict__ G,
                                                    const float* __restrict__ Wsum,
                                                    float* __restrict__ partials) {
    __shared__ float red[4];
    const int t    = threadIdx.x;
    const int w    = __builtin_amdgcn_readfirstlane(t >> 6);  // uniform wave id
    const int lane = t & 63;
    const int wave = blockIdx.x * 4 + w;     // 0..4607
    const int iblk = wave % 24;              // 64-wide i-block
    const int brng = wave / 24;              // 0..191, BPW b's each
    const int b0   = brng * BPW;
    const int i    = iblk * 64 + lane;
    const int ib   = iblk >> 1;              // uniform within wave

    // Loop-invariant Wsum row for this lane's i (144 B, L2/L3-hit).
    float4 wv[9];
    const float4* wsv = (const float4*)(Wsum + (size_t)i * NJ);
    #pragma unroll
    for (int k4 = 0; k4 < 9; ++k4) wv[k4] = wsv[k4];

    const float* xp    = X + (size_t)b0 * DI + i;     // coalesced, lane<->i
    const float* gbase = G + (size_t)b0 * GROW + (size_t)ib * NJ;  // wave-uniform

    float s = 0.f;
    #pragma unroll
    for (int bb = 0; bb < BPW; ++bb) {
        const float4* g4 = (const float4*)(gbase + (size_t)bb * GROW);
        float x = xp[(size_t)bb * DI];
        float d0 = 0.f, d1 = 0.f;     // two partials halve the dep chain
        #pragma unroll
        for (int k4 = 0; k4 < 9; ++k4) {
            float4 gv = g4[k4];       // uniform address -> scalar loads
            d0 = fmaf(wv[k4].x, gv.x, d0);
            d1 = fmaf(wv[k4].y, gv.y, d1);
            d0 = fmaf(wv[k4].z, gv.z, d0);
            d1 = fmaf(wv[k4].w, gv.w, d1);
        }
        s = fmaf(x, d0 + d1, s);
    }

    #pragma unroll
    for (int off = 1; off < 64; off <<= 1) s += __shfl_xor(s, off, 64);
    if (lane == 0) red[w] = s;
    __syncthreads();
    if (t == 0)
        partials[blockIdx.x] = (red[0] + red[1]) + (red[2] + red[3]);
}

// ---- Kernel 3: final reduce + square (1 block) ----
__global__ __launch_bounds__(256) void finish_kernel(const float* __restrict__ partials,
                                                     float* __restrict__ out) {
    __shared__ float red[4];
    const int t = threadIdx.x;
    float s = 0.f;
    for (int e = t; e < K2_BLOCKS; e += 256) s += partials[e];
    #pragma unroll
    for (int off = 1; off < 64; off <<= 1) s += __shfl_xor(s, off, 64);
    const int w = t >> 6, lane = t & 63;
    if (lane == 0) red[w] = s;
    __syncthreads();
    if (t == 0) {
        float tot = (red[0] + red[1]) + (red[2] + red[3]);
        out[0] = tot * tot;
    }
}

extern "C" void kernel_launch(void* const* d_in, const int* in_sizes, int n_in,
                              void* d_out, int out_size, void* d_ws, size_t ws_size,
                              hipStream_t stream) {
    const float* X = (const float*)d_in[0];  // [1536,1536]
    const float* W = (const float*)d_in[1];  // [1536,4608]
    const float* G = (const float*)d_in[2];  // [1536,12,36]
    float* out = (float*)d_out;

    float* Wsum     = (float*)d_ws;                 // 55296 floats
    float* partials = Wsum + (size_t)DI * NJ;       // 1152 floats

    // Kernel 1: 27648 waves = 6912 blocks x 4 waves.
    wsum_kernel<<<(DI * 18) / 4, 256, 0, stream>>>(W, Wsum);
    // Kernel 2: 1152 blocks x 256 threads -> plain partials (no atomics).
    gated_kernel<<<K2_BLOCKS, 256, 0, stream>>>(X, G, Wsum, partials);
    // Kernel 3: single block reduces 1152 partials and squares.
    finish_kernel<<<1, 256, 0, stream>>>(partials, out);
}

// Round 6
// 89.881 us; speedup vs baseline: 1.3845x; 1.0112x over previous
//
#include <hip/hip_runtime.h>

// s = sum_{b,i,j} X[b,i] W[i,j] G[b,i/128,j/128]; out = s^2.
// Factor over j:  s = sum_{i,jb} Wsum[i,jb] * H[i,jb],
//   Wsum[i,jb] = sum_{c<128} W[i, jb*128+c]
//   H[i,jb]    = sum_b X[b,i] * G[b, i/128, jb]
// K1: Wsum (HBM-bound, 28.3 MB mandatory read).
// K2: lane<->i; per-b: s += x * dot36(WsumRow_i, G_row). R5 post-mortem:
//     compiler allocated 32 VGPRs (< the 36-float Wsum row!) and re-loaded
//     wv from L2 every iteration (72 reloads/wave) -> ~20 us. Fix: pin wv
//     in VGPRs via empty asm (blocks rematerialization) + launch_bounds
//     (256,4) to allow a ~128-VGPR budget. No atomics (R4: XCD ping-pong).
// K3: 1-block finish: reduce 1152 partials, square.

#define B_DIM 1536
#define DI    1536
#define DO    4608
#define NI    12
#define NJ    36
#define GROW  (NI * NJ)            // 432 floats per G batch-row
#define BPW   8                    // b's per wave in kernel 2
#define K2_WAVES  (24 * (B_DIM / BPW))   // 24 i-blocks x 192 b-ranges = 4608
#define K2_BLOCKS (K2_WAVES / 4)         // 1152

// ---- Kernel 1: Wsum[i][jb]; wave handles (i, jb-pair); lane loads float4 ----
__global__ __launch_bounds__(256) void wsum_kernel(const float* __restrict__ W,
                                                   float* __restrict__ Wsum) {
    int g    = blockIdx.x * 4 + (threadIdx.x >> 6);  // global wave id, 27648 total
    int lane = threadIdx.x & 63;
    int i = g / 18;          // row
    int w = g - i * 18;      // jb-pair: covers jb = 2w, 2w+1 (256 floats, 1 KB)
    const float4* p = (const float4*)(W + (size_t)i * DO + (size_t)w * 256);
    float4 v = p[lane];
    float s = (v.x + v.y) + (v.z + v.w);
    #pragma unroll
    for (int off = 16; off > 0; off >>= 1) s += __shfl_xor(s, off, 64);
    if (lane == 0)  Wsum[i * NJ + 2 * w]     = s;
    if (lane == 32) Wsum[i * NJ + 2 * w + 1] = s;
}

// ---- Kernel 2: s += x * dot36(WsumRow, Grow); plain per-block partial ----
__global__ __launch_bounds__(256, 4) void gated_kernel(const float* __restrict__ X,
                                                       const float* __restrict__ G,
                                                       const float* __restrict__ Wsum,
                                                       float* __restrict__ partials) {
    __shared__ float red[4];
    const int t    = threadIdx.x;
    const int w    = __builtin_amdgcn_readfirstlane(t >> 6);  // uniform wave id
    const int lane = t & 63;
    const int wave = blockIdx.x * 4 + w;     // 0..4607
    const int iblk = wave % 24;              // 64-wide i-block
    const int brng = wave / 24;              // 0..191, BPW b's each
    const int b0   = brng * BPW;
    const int i    = iblk * 64 + lane;
    const int ib   = iblk >> 1;              // uniform within wave

    // Loop-invariant Wsum row for this lane's i (144 B, L2/L3-hit), loaded
    // ONCE and pinned in VGPRs: the empty asm writes each element, making
    // rematerialization/reload illegal for the allocator.
    float wv[NJ];
    {
        const float4* wsv = (const float4*)(Wsum + (size_t)i * NJ);
        #pragma unroll
        for (int k4 = 0; k4 < 9; ++k4) {
            float4 v = wsv[k4];
            wv[4*k4+0] = v.x; wv[4*k4+1] = v.y;
            wv[4*k4+2] = v.z; wv[4*k4+3] = v.w;
        }
    }
    #pragma unroll
    for (int k = 0; k < NJ; ++k) asm("" : "+v"(wv[k]));   // pin in registers

    const float* xp    = X + (size_t)b0 * DI + i;     // coalesced, lane<->i
    const float* gbase = G + (size_t)b0 * GROW + (size_t)ib * NJ;  // wave-uniform

    float s = 0.f;
    #pragma unroll
    for (int bb = 0; bb < BPW; ++bb) {
        const float4* g4 = (const float4*)(gbase + (size_t)bb * GROW);
        float x = xp[(size_t)bb * DI];
        float d0 = 0.f, d1 = 0.f;     // two partials halve the dep chain
        #pragma unroll
        for (int k4 = 0; k4 < 9; ++k4) {
            float4 gv = g4[k4];       // uniform address -> scalar loads
            d0 = fmaf(wv[4*k4+0], gv.x, d0);
            d1 = fmaf(wv[4*k4+1], gv.y, d1);
            d0 = fmaf(wv[4*k4+2], gv.z, d0);
            d1 = fmaf(wv[4*k4+3], gv.w, d1);
        }
        s = fmaf(x, d0 + d1, s);
    }

    #pragma unroll
    for (int off = 1; off < 64; off <<= 1) s += __shfl_xor(s, off, 64);
    if (lane == 0) red[w] = s;
    __syncthreads();
    if (t == 0)
        partials[blockIdx.x] = (red[0] + red[1]) + (red[2] + red[3]);
}

// ---- Kernel 3: final reduce + square (1 block) ----
__global__ __launch_bounds__(256) void finish_kernel(const float* __restrict__ partials,
                                                     float* __restrict__ out) {
    __shared__ float red[4];
    const int t = threadIdx.x;
    float s = 0.f;
    for (int e = t; e < K2_BLOCKS; e += 256) s += partials[e];
    #pragma unroll
    for (int off = 1; off < 64; off <<= 1) s += __shfl_xor(s, off, 64);
    const int w = t >> 6, lane = t & 63;
    if (lane == 0) red[w] = s;
    __syncthreads();
    if (t == 0) {
        float tot = (red[0] + red[1]) + (red[2] + red[3]);
        out[0] = tot * tot;
    }
}

extern "C" void kernel_launch(void* const* d_in, const int* in_sizes, int n_in,
                              void* d_out, int out_size, void* d_ws, size_t ws_size,
                              hipStream_t stream) {
    const float* X = (const float*)d_in[0];  // [1536,1536]
    const float* W = (const float*)d_in[1];  // [1536,4608]
    const float* G = (const float*)d_in[2];  // [1536,12,36]
    float* out = (float*)d_out;

    float* Wsum     = (float*)d_ws;                 // 55296 floats
    float* partials = Wsum + (size_t)DI * NJ;       // 1152 floats

    // Kernel 1: 27648 waves = 6912 blocks x 4 waves.
    wsum_kernel<<<(DI * 18) / 4, 256, 0, stream>>>(W, Wsum);
    // Kernel 2: 1152 blocks x 256 threads -> plain partials (no atomics).
    gated_kernel<<<K2_BLOCKS, 256, 0, stream>>>(X, G, Wsum, partials);
    // Kernel 3: single block reduces 1152 partials and squares.
    finish_kernel<<<1, 256, 0, stream>>>(partials, out);
}

// Round 7
// 88.241 us; speedup vs baseline: 1.4102x; 1.0186x over previous
//
#include <hip/hip_runtime.h>

// s = sum_{b,i,j} X[b,i] W[i,j] G[b,i/128,j/128]; out = s^2.
// Factor over j:  s = sum_{i,jb} Wsum[i,jb] * H[i,jb],
//   Wsum[i,jb] = sum_{c<128} W[i, jb*128+c]
//   H[i,jb]    = sum_b X[b,i] * G[b, i/128, jb]
// K1: WsumT[jb][i] (TRANSPOSED so k2's per-lane row read is coalesced).
// K2: lane<->i. R6 post-mortem: ~20 us came from per-wave latency chains —
//     72 cold scalar G loads (~900 cyc HBM each, un-pipelinable: 288 SGPRs
//     needed) + a 144 B-stride Wsum gather (576 cachelines/wave). Fix:
//     G staged once per block into LDS via coalesced vector loads, inner
//     loop uses uniform-address LDS broadcasts; Wsum read via WsumT
//     coalesced. No atomics (R4: cross-XCD ping-pong cost ~19 ns/RMW).
// K3: 1-block finish: reduce 1152 partials, square.

#define B_DIM 1536
#define DI    1536
#define DO    4608
#define NI    12
#define NJ    36
#define GROW  (NI * NJ)            // 432 floats per G batch-row
#define BPW   8                    // b's per wave in kernel 2
#define K2_WAVES  (24 * (B_DIM / BPW))   // 24 i-blocks x 192 b-ranges = 4608
#define K2_BLOCKS (K2_WAVES / 4)         // 1152

// ---- Kernel 1: WsumT[jb][i]; wave handles (i, jb-pair); lane loads float4 ----
__global__ __launch_bounds__(256) void wsum_kernel(const float* __restrict__ W,
                                                   float* __restrict__ WsumT) {
    int g    = blockIdx.x * 4 + (threadIdx.x >> 6);  // global wave id, 27648 total
    int lane = threadIdx.x & 63;
    int i = g / 18;          // row
    int w = g - i * 18;      // jb-pair: covers jb = 2w, 2w+1 (256 floats, 1 KB)
    const float4* p = (const float4*)(W + (size_t)i * DO + (size_t)w * 256);
    float4 v = p[lane];
    float s = (v.x + v.y) + (v.z + v.w);
    #pragma unroll
    for (int off = 16; off > 0; off >>= 1) s += __shfl_xor(s, off, 64);
    // lanes 0..31 hold block jb=2w, lanes 32..63 hold jb=2w+1
    if (lane == 0)  WsumT[(size_t)(2 * w)     * DI + i] = s;
    if (lane == 32) WsumT[(size_t)(2 * w + 1) * DI + i] = s;
}

// ---- Kernel 2: s += x * dot36(wv, G_row); G via LDS broadcast ----
__global__ __launch_bounds__(256, 4) void gated_kernel(const float* __restrict__ X,
                                                       const float* __restrict__ G,
                                                       const float* __restrict__ WsumT,
                                                       float* __restrict__ partials) {
    __shared__ float4 gs4[BPW * 72 / 4];   // 8 b x 2 ib x 36 floats = 2304 B
    __shared__ float red[4];
    float* gs = (float*)gs4;

    const int t     = threadIdx.x;
    const int w     = t >> 6;
    const int lane  = t & 63;
    const int wave0 = blockIdx.x * 4;
    const int brng  = wave0 / 24;          // block-uniform (4 | 24)
    const int a     = (wave0 % 24) >> 2;   // block's iblk quad -> ib pair {2a,2a+1}
    const int b0    = brng * BPW;
    const int iblk  = (wave0 % 24) + w;
    const int i     = iblk * 64 + lane;
    const int d     = w >> 1;              // which staged ib row this wave uses

    // Cooperative stage of G slice [b0..b0+7] x [2a..2a+1] x [0..35]:
    // contiguous 72-float runs per b -> coalesced; full MLP, one drain.
    for (int e = t; e < BPW * 72; e += 256) {
        int b = e / 72, r = e - b * 72;
        gs[e] = G[(size_t)(b0 + b) * GROW + (size_t)(2 * a) * NJ + r];
    }

    // Loop-invariant Wsum slice, coalesced: wv[k] = WsumT[k][i].
    float wv[NJ];
    #pragma unroll
    for (int k = 0; k < NJ; ++k) wv[k] = WsumT[(size_t)k * DI + i];
    #pragma unroll
    for (int k = 0; k < NJ; ++k) asm("" : "+v"(wv[k]));   // keep resident

    __syncthreads();

    const float* xp = X + (size_t)b0 * DI + i;     // coalesced, lane<->i
    float s = 0.f;
    #pragma unroll
    for (int bb = 0; bb < BPW; ++bb) {
        float x = xp[(size_t)bb * DI];
        const float4* gp = (const float4*)(gs + bb * 72 + d * 36);  // uniform addr
        float d0 = 0.f, d1 = 0.f;
        #pragma unroll
        for (int k4 = 0; k4 < 9; ++k4) {
            float4 gv = gp[k4];                    // ds_read_b128 broadcast
            d0 = fmaf(wv[4*k4+0], gv.x, d0);
            d1 = fmaf(wv[4*k4+1], gv.y, d1);
            d0 = fmaf(wv[4*k4+2], gv.z, d0);
            d1 = fmaf(wv[4*k4+3], gv.w, d1);
        }
        s = fmaf(x, d0 + d1, s);
    }

    #pragma unroll
    for (int off = 1; off < 64; off <<= 1) s += __shfl_xor(s, off, 64);
    if (lane == 0) red[w] = s;
    __syncthreads();
    if (t == 0)
        partials[blockIdx.x] = (red[0] + red[1]) + (red[2] + red[3]);
}

// ---- Kernel 3: final reduce + square (1 block) ----
__global__ __launch_bounds__(256) void finish_kernel(const float* __restrict__ partials,
                                                     float* __restrict__ out) {
    __shared__ float red[4];
    const int t = threadIdx.x;
    float s = 0.f;
    for (int e = t; e < K2_BLOCKS; e += 256) s += partials[e];
    #pragma unroll
    for (int off = 1; off < 64; off <<= 1) s += __shfl_xor(s, off, 64);
    const int w = t >> 6, lane = t & 63;
    if (lane == 0) red[w] = s;
    __syncthreads();
    if (t == 0) {
        float tot = (red[0] + red[1]) + (red[2] + red[3]);
        out[0] = tot * tot;
    }
}

extern "C" void kernel_launch(void* const* d_in, const int* in_sizes, int n_in,
                              void* d_out, int out_size, void* d_ws, size_t ws_size,
                              hipStream_t stream) {
    const float* X = (const float*)d_in[0];  // [1536,1536]
    const float* W = (const float*)d_in[1];  // [1536,4608]
    const float* G = (const float*)d_in[2];  // [1536,12,36]
    float* out = (float*)d_out;

    float* WsumT    = (float*)d_ws;                 // 55296 floats, [36][1536]
    float* partials = WsumT + (size_t)NJ * DI;      // 1152 floats

    // Kernel 1: 27648 waves = 6912 blocks x 4 waves.
    wsum_kernel<<<(DI * 18) / 4, 256, 0, stream>>>(W, WsumT);
    // Kernel 2: 1152 blocks x 256 threads -> plain partials (no atomics).
    gated_kernel<<<K2_BLOCKS, 256, 0, stream>>>(X, G, WsumT, partials);
    // Kernel 3: single block reduces 1152 partials and squares.
    finish_kernel<<<1, 256, 0, stream>>>(partials, out);
}